// Round 1
// baseline (2711.393 us; speedup 1.0000x reference)
//
#include <hip/hip_runtime.h>

#define NN 16384
#define EE 262144
#define ET (EE + NN)
#define EMB 300
#define H2 600
#define NL 5
#define BN_EPS 1e-5f

// ---------------- init h: sum of 6 embedding lookups ----------------
__global__ void k_init_h(const int* __restrict__ x,
                         const float* __restrict__ ta, const float* __restrict__ td,
                         const float* __restrict__ tc, const float* __restrict__ th,
                         const float* __restrict__ tar, const float* __restrict__ tch,
                         float* __restrict__ h) {
    int i = blockIdx.x;
    int i0 = x[i*6+0], i1 = x[i*6+1], i2 = x[i*6+2];
    int i3 = x[i*6+3], i4 = x[i*6+4], i5 = x[i*6+5];
    const float* p0 = ta  + (size_t)i0*EMB;
    const float* p1 = td  + (size_t)i1*EMB;
    const float* p2 = tc  + (size_t)i2*EMB;
    const float* p3 = th  + (size_t)i3*EMB;
    const float* p4 = tar + (size_t)i4*EMB;
    const float* p5 = tch + (size_t)i5*EMB;
    float* ho = h + (size_t)i*EMB;
    for (int j = threadIdx.x; j < EMB; j += blockDim.x)
        ho[j] = p0[j] + p1[j] + p2[j] + p3[j] + p4[j] + p5[j];
}

// ---------------- scatter-add messages (atomics) ----------------
// 4 edges per 256-thread block; 64 lanes per edge.
__global__ void k_scatter(const int* __restrict__ ei, const int* __restrict__ eattr,
                          const float* __restrict__ h, const float* __restrict__ E1,
                          const float* __restrict__ E2, float* __restrict__ agg) {
    int e = blockIdx.x * 4 + (threadIdx.x >> 6);
    int lane = threadIdx.x & 63;
    if (e >= ET) return;
    int s, d, a0, a1;
    if (e < EE) {
        s = ei[e]; d = ei[EE + e];
        a0 = eattr[2*e]; a1 = eattr[2*e + 1];
    } else {
        s = e - EE; d = s; a0 = 4; a1 = 0;
    }
    const float* hs = h + (size_t)s*EMB;
    const float* p1 = E1 + (size_t)a0*EMB;
    const float* p2 = E2 + (size_t)a1*EMB;
    float* ad = agg + (size_t)d*EMB;
    for (int j = lane; j < EMB; j += 64)
        atomicAdd(&ad[j], hs[j] + p1[j] + p2[j]);
}

// ---------------- f32 tiled GEMM: C = op(A@B + bias), 64x64 tile ----------------
template<bool RELU>
__global__ __launch_bounds__(256) void k_gemm(const float* __restrict__ A,
                                              const float* __restrict__ B,
                                              const float* __restrict__ bias,
                                              float* __restrict__ C,
                                              int M, int K, int Nc) {
    __shared__ float As[16][64];
    __shared__ float Bs[16][64];
    int tid = threadIdx.x;
    int tx = tid & 15, ty = tid >> 4;
    int m0 = blockIdx.y * 64, n0 = blockIdx.x * 64;
    float acc[4][4] = {};
    int lm = tid >> 2, quad = tid & 3;   // A-tile load coords
    int lk = tid >> 4, nq = tid & 15;    // B-tile load coords

    for (int k0 = 0; k0 < K; k0 += 16) {
        {   // load 64x16 A tile (K%4==0 so float4 is all-or-nothing)
            int k = k0 + quad*4;
            float4 v = make_float4(0.f,0.f,0.f,0.f);
            if (k + 3 < K)
                v = *reinterpret_cast<const float4*>(A + (size_t)(m0+lm)*K + k);
            As[quad*4+0][lm] = v.x; As[quad*4+1][lm] = v.y;
            As[quad*4+2][lm] = v.z; As[quad*4+3][lm] = v.w;
        }
        {   // load 16x64 B tile (Nc%4==0)
            int kb = k0 + lk;
            int n = n0 + nq*4;
            float4 v = make_float4(0.f,0.f,0.f,0.f);
            if (kb < K && n + 3 < Nc)
                v = *reinterpret_cast<const float4*>(B + (size_t)kb*Nc + n);
            *reinterpret_cast<float4*>(&Bs[lk][nq*4]) = v;
        }
        __syncthreads();
        #pragma unroll
        for (int kk = 0; kk < 16; ++kk) {
            float a[4], b[4];
            #pragma unroll
            for (int i = 0; i < 4; ++i) a[i] = As[kk][ty*4+i];
            #pragma unroll
            for (int j = 0; j < 4; ++j) b[j] = Bs[kk][tx*4+j];
            #pragma unroll
            for (int i = 0; i < 4; ++i)
                #pragma unroll
                for (int j = 0; j < 4; ++j)
                    acc[i][j] += a[i]*b[j];
        }
        __syncthreads();
    }
    #pragma unroll
    for (int i = 0; i < 4; ++i) {
        int m = m0 + ty*4 + i;
        #pragma unroll
        for (int j = 0; j < 4; ++j) {
            int n = n0 + tx*4 + j;
            if (n < Nc) {
                float v = acc[i][j] + bias[n];
                if (RELU) v = fmaxf(v, 0.f);
                C[(size_t)m*Nc + n] = v;
            }
        }
    }
}

// ---------------- BN stats: per-channel partial sums (coalesced rows) ----------------
__global__ void k_bnstats(const float* __restrict__ h,
                          float* __restrict__ sums, float* __restrict__ sumsq) {
    int c = threadIdx.x;
    if (c >= EMB) return;
    int r0 = blockIdx.x * 128;
    float s = 0.f, s2 = 0.f;
    for (int r = r0; r < r0 + 128; ++r) {
        float v = h[(size_t)r*EMB + c];
        s += v; s2 += v*v;
    }
    atomicAdd(&sums[c], s);
    atomicAdd(&sumsq[c], s2);
}

__global__ void k_bnfin(const float* __restrict__ sums, const float* __restrict__ sumsq,
                        float* __restrict__ mu, float* __restrict__ rs) {
    int c = threadIdx.x;
    if (c >= EMB) return;
    float m = sums[c] * (1.f/NN);
    float v = sumsq[c] * (1.f/NN) - m*m;
    mu[c] = m;
    rs[c] = rsqrtf(v + BN_EPS);
}

__global__ void k_bnapply(const float* __restrict__ h, const float* __restrict__ mu,
                          const float* __restrict__ rs, const float* __restrict__ gamma,
                          const float* __restrict__ beta, float* __restrict__ out, int relu) {
    const int total = NN*EMB;
    for (int idx = blockIdx.x*blockDim.x + threadIdx.x; idx < total;
         idx += gridDim.x*blockDim.x) {
        int c = idx % EMB;
        float v = (h[idx] - mu[c]) * rs[c] * gamma[c] + beta[c];
        if (relu) v = fmaxf(v, 0.f);
        out[idx] = v;
    }
}

extern "C" void kernel_launch(void* const* d_in, const int* in_sizes, int n_in,
                              void* d_out, int out_size, void* d_ws, size_t ws_size,
                              hipStream_t stream) {
    const int*   x     = (const int*)d_in[0];
    const int*   ei    = (const int*)d_in[1];
    const int*   eattr = (const int*)d_in[2];
    const float* ta    = (const float*)d_in[3];
    const float* td    = (const float*)d_in[4];
    const float* tc    = (const float*)d_in[5];
    const float* th    = (const float*)d_in[6];
    const float* tar   = (const float*)d_in[7];
    const float* tch   = (const float*)d_in[8];
    const float* W1    = (const float*)d_in[9];
    const float* b1    = (const float*)d_in[10];
    const float* W2    = (const float*)d_in[11];
    const float* b2    = (const float*)d_in[12];
    const float* ee1   = (const float*)d_in[13];
    const float* ee2   = (const float*)d_in[14];
    const float* gam   = (const float*)d_in[15];
    const float* bet   = (const float*)d_in[16];
    float* out = (float*)d_out;

    char* ws = (char*)d_ws;
    const size_t H_BYTES = (size_t)NN*EMB*4;      // 19,660,800
    const size_t T_BYTES = (size_t)NN*H2*4;       // 39,321,600
    float* h    = (float*)(ws);
    float* agg  = (float*)(ws + H_BYTES);
    float* t    = (float*)(ws + 2*H_BYTES);
    float* stat = (float*)(ws + 2*H_BYTES + T_BYTES);
    float* sums = stat;          // 300
    float* sumsq= stat + 300;    // 300
    float* mu   = stat + 600;    // 300
    float* rs   = stat + 900;    // 300

    k_init_h<<<NN, 256, 0, stream>>>(x, ta, td, tc, th, tar, tch, h);

    for (int l = 0; l < NL; ++l) {
        hipMemsetAsync(agg, 0, H_BYTES, stream);
        k_scatter<<<ET/4, 256, 0, stream>>>(ei, eattr, h,
                                            ee1 + (size_t)l*6*EMB,
                                            ee2 + (size_t)l*3*EMB, agg);
        k_gemm<true ><<<dim3(10,256), 256, 0, stream>>>(agg, W1 + (size_t)l*EMB*H2,
                                                        b1 + (size_t)l*H2, t,
                                                        NN, EMB, H2);
        k_gemm<false><<<dim3(5,256), 256, 0, stream>>>(t, W2 + (size_t)l*H2*EMB,
                                                       b2 + (size_t)l*EMB, h,
                                                       NN, H2, EMB);
        hipMemsetAsync(stat, 0, 2400, stream);
        k_bnstats<<<NN/128, 320, 0, stream>>>(h, sums, sumsq);
        k_bnfin<<<1, 320, 0, stream>>>(sums, sumsq, mu, rs);
        float* dst = (l == NL-1) ? out : h;
        k_bnapply<<<2048, 256, 0, stream>>>(h, mu, rs,
                                            gam + (size_t)l*EMB, bet + (size_t)l*EMB,
                                            dst, (l < NL-1) ? 1 : 0);
    }
}

// Round 2
// 1487.169 us; speedup vs baseline: 1.8232x; 1.8232x over previous
//
#include <hip/hip_runtime.h>

#define NN 16384
#define EE 262144
#define EMB 300
#define H2 600
#define NL 5
#define BN_EPS 1e-5f

// ---------------- init h: sum of 6 embedding lookups ----------------
__global__ void k_init_h(const int* __restrict__ x,
                         const float* __restrict__ ta, const float* __restrict__ td,
                         const float* __restrict__ tc, const float* __restrict__ th,
                         const float* __restrict__ tar, const float* __restrict__ tch,
                         float* __restrict__ h) {
    int i = blockIdx.x;
    int i0 = x[i*6+0], i1 = x[i*6+1], i2 = x[i*6+2];
    int i3 = x[i*6+3], i4 = x[i*6+4], i5 = x[i*6+5];
    const float* p0 = ta  + (size_t)i0*EMB;
    const float* p1 = td  + (size_t)i1*EMB;
    const float* p2 = tc  + (size_t)i2*EMB;
    const float* p3 = th  + (size_t)i3*EMB;
    const float* p4 = tar + (size_t)i4*EMB;
    const float* p5 = tch + (size_t)i5*EMB;
    float* ho = h + (size_t)i*EMB;
    for (int j = threadIdx.x; j < EMB; j += blockDim.x)
        ho[j] = p0[j] + p1[j] + p2[j] + p3[j] + p4[j] + p5[j];
}

// ---------------- CSR build: histogram of dst ----------------
__global__ void k_hist(const int* __restrict__ ei, int* __restrict__ cnt) {
    int e = blockIdx.x * blockDim.x + threadIdx.x;
    if (e < EE) atomicAdd(&cnt[ei[EE + e]], 1);
}

// ---------------- exclusive scan of 16384 counts (single block) ----------------
__global__ __launch_bounds__(1024) void k_scan(const int* __restrict__ cnt,
                                               int* __restrict__ row_off,
                                               int* __restrict__ cursor) {
    __shared__ int lds[1024];
    int t = threadIdx.x;
    int base = t * 16;
    int local[16];
    int total = 0;
    #pragma unroll
    for (int i = 0; i < 16; ++i) { local[i] = cnt[base + i]; total += local[i]; }
    lds[t] = total;
    __syncthreads();
    // Hillis-Steele inclusive scan over 1024 partials
    for (int off = 1; off < 1024; off <<= 1) {
        int v = (t >= off) ? lds[t - off] : 0;
        __syncthreads();
        lds[t] += v;
        __syncthreads();
    }
    int run = lds[t] - total;   // exclusive prefix for this thread's chunk
    #pragma unroll
    for (int i = 0; i < 16; ++i) {
        row_off[base + i] = run;
        cursor[base + i]  = run;
        run += local[i];
    }
    if (t == 0) row_off[NN] = EE;
}

// ---------------- permute edges into CSR order, pack src + attr-combo ----------------
__global__ void k_fill(const int* __restrict__ ei, const int* __restrict__ eattr,
                       int* __restrict__ cursor, int* __restrict__ packed) {
    int e = blockIdx.x * blockDim.x + threadIdx.x;
    if (e >= EE) return;
    int d  = ei[EE + e];
    int s  = ei[e];
    int a0 = eattr[2*e], a1 = eattr[2*e + 1];   // both in 0..2
    int pos = atomicAdd(&cursor[d], 1);
    packed[pos] = s | ((a0*3 + a1) << 16);
}

// ---------------- per-node gather aggregation ----------------
// 4 waves / block, 1 wave per node. LDS holds 10 precombined edge-emb rows:
// rows 0..8 = E1[a0]+E2[a1] for combo a0*3+a1, row 9 = self-loop E1[4]+E2[0].
__global__ __launch_bounds__(256) void k_aggregate(const int* __restrict__ row_off,
                                                   const int* __restrict__ packed,
                                                   const float* __restrict__ h,
                                                   const float* __restrict__ E1,
                                                   const float* __restrict__ E2,
                                                   float* __restrict__ agg) {
    __shared__ float comb[10 * EMB];
    int tid = threadIdx.x;
    for (int idx = tid; idx < 10 * EMB; idx += 256) {
        int r = idx / EMB, c = idx % EMB;
        float v;
        if (r < 9) v = E1[(r/3)*EMB + c] + E2[(r%3)*EMB + c];
        else       v = E1[4*EMB + c]     + E2[0*EMB + c];
        comb[idx] = v;
    }
    __syncthreads();

    int n    = blockIdx.x * 4 + (tid >> 6);
    int lane = tid & 63;
    // channels: lane, lane+64, lane+128, lane+192, lane+256 (<300)
    float acc[5];
    const float* hn = h + (size_t)n*EMB;
    #pragma unroll
    for (int k = 0; k < 5; ++k) {
        int c = lane + 64*k;
        acc[k] = (c < EMB) ? (hn[c] + comb[9*EMB + c]) : 0.f;   // self loop
    }
    int j0 = row_off[n], j1 = row_off[n+1];
    for (int j = j0; j < j1; ++j) {
        int p = packed[j];
        int s = p & 0xFFFF;
        int cb = p >> 16;
        const float* hs = h + (size_t)s*EMB;
        const float* cc = comb + cb*EMB;
        #pragma unroll
        for (int k = 0; k < 5; ++k) {
            int c = lane + 64*k;
            if (c < EMB) acc[k] += hs[c] + cc[c];
        }
    }
    float* ao = agg + (size_t)n*EMB;
    #pragma unroll
    for (int k = 0; k < 5; ++k) {
        int c = lane + 64*k;
        if (c < EMB) ao[c] = acc[k];
    }
}

// ---------------- f32 tiled GEMM: C = op(A@B + bias), 64x64 tile ----------------
template<bool RELU>
__global__ __launch_bounds__(256) void k_gemm(const float* __restrict__ A,
                                              const float* __restrict__ B,
                                              const float* __restrict__ bias,
                                              float* __restrict__ C,
                                              int M, int K, int Nc) {
    __shared__ float As[16][64];
    __shared__ float Bs[16][64];
    int tid = threadIdx.x;
    int tx = tid & 15, ty = tid >> 4;
    int m0 = blockIdx.y * 64, n0 = blockIdx.x * 64;
    float acc[4][4] = {};
    int lm = tid >> 2, quad = tid & 3;   // A-tile load coords
    int lk = tid >> 4, nq = tid & 15;    // B-tile load coords

    for (int k0 = 0; k0 < K; k0 += 16) {
        {   // load 64x16 A tile (K%4==0 so float4 is all-or-nothing)
            int k = k0 + quad*4;
            float4 v = make_float4(0.f,0.f,0.f,0.f);
            if (k + 3 < K)
                v = *reinterpret_cast<const float4*>(A + (size_t)(m0+lm)*K + k);
            As[quad*4+0][lm] = v.x; As[quad*4+1][lm] = v.y;
            As[quad*4+2][lm] = v.z; As[quad*4+3][lm] = v.w;
        }
        {   // load 16x64 B tile (Nc%4==0)
            int kb = k0 + lk;
            int n = n0 + nq*4;
            float4 v = make_float4(0.f,0.f,0.f,0.f);
            if (kb < K && n + 3 < Nc)
                v = *reinterpret_cast<const float4*>(B + (size_t)kb*Nc + n);
            *reinterpret_cast<float4*>(&Bs[lk][nq*4]) = v;
        }
        __syncthreads();
        #pragma unroll
        for (int kk = 0; kk < 16; ++kk) {
            float a[4], b[4];
            #pragma unroll
            for (int i = 0; i < 4; ++i) a[i] = As[kk][ty*4+i];
            #pragma unroll
            for (int j = 0; j < 4; ++j) b[j] = Bs[kk][tx*4+j];
            #pragma unroll
            for (int i = 0; i < 4; ++i)
                #pragma unroll
                for (int j = 0; j < 4; ++j)
                    acc[i][j] += a[i]*b[j];
        }
        __syncthreads();
    }
    #pragma unroll
    for (int i = 0; i < 4; ++i) {
        int m = m0 + ty*4 + i;
        #pragma unroll
        for (int j = 0; j < 4; ++j) {
            int n = n0 + tx*4 + j;
            if (n < Nc) {
                float v = acc[i][j] + bias[n];
                if (RELU) v = fmaxf(v, 0.f);
                C[(size_t)m*Nc + n] = v;
            }
        }
    }
}

// ---------------- BN stats: per-channel partial sums (coalesced rows) ----------------
__global__ void k_bnstats(const float* __restrict__ h,
                          float* __restrict__ sums, float* __restrict__ sumsq) {
    int c = threadIdx.x;
    if (c >= EMB) return;
    int r0 = blockIdx.x * 128;
    float s = 0.f, s2 = 0.f;
    for (int r = r0; r < r0 + 128; ++r) {
        float v = h[(size_t)r*EMB + c];
        s += v; s2 += v*v;
    }
    atomicAdd(&sums[c], s);
    atomicAdd(&sumsq[c], s2);
}

__global__ void k_bnfin(const float* __restrict__ sums, const float* __restrict__ sumsq,
                        float* __restrict__ mu, float* __restrict__ rs) {
    int c = threadIdx.x;
    if (c >= EMB) return;
    float m = sums[c] * (1.f/NN);
    float v = sumsq[c] * (1.f/NN) - m*m;
    mu[c] = m;
    rs[c] = rsqrtf(v + BN_EPS);
}

__global__ void k_bnapply(const float* __restrict__ h, const float* __restrict__ mu,
                          const float* __restrict__ rs, const float* __restrict__ gamma,
                          const float* __restrict__ beta, float* __restrict__ out, int relu) {
    const int total = NN*EMB;
    for (int idx = blockIdx.x*blockDim.x + threadIdx.x; idx < total;
         idx += gridDim.x*blockDim.x) {
        int c = idx % EMB;
        float v = (h[idx] - mu[c]) * rs[c] * gamma[c] + beta[c];
        if (relu) v = fmaxf(v, 0.f);
        out[idx] = v;
    }
}

extern "C" void kernel_launch(void* const* d_in, const int* in_sizes, int n_in,
                              void* d_out, int out_size, void* d_ws, size_t ws_size,
                              hipStream_t stream) {
    const int*   x     = (const int*)d_in[0];
    const int*   ei    = (const int*)d_in[1];
    const int*   eattr = (const int*)d_in[2];
    const float* ta    = (const float*)d_in[3];
    const float* td    = (const float*)d_in[4];
    const float* tc    = (const float*)d_in[5];
    const float* th    = (const float*)d_in[6];
    const float* tar   = (const float*)d_in[7];
    const float* tch   = (const float*)d_in[8];
    const float* W1    = (const float*)d_in[9];
    const float* b1    = (const float*)d_in[10];
    const float* W2    = (const float*)d_in[11];
    const float* b2    = (const float*)d_in[12];
    const float* ee1   = (const float*)d_in[13];
    const float* ee2   = (const float*)d_in[14];
    const float* gam   = (const float*)d_in[15];
    const float* bet   = (const float*)d_in[16];
    float* out = (float*)d_out;

    char* ws = (char*)d_ws;
    const size_t H_BYTES = (size_t)NN*EMB*4;      // 19,660,800
    const size_t T_BYTES = (size_t)NN*H2*4;       // 39,321,600
    float* h    = (float*)(ws);
    float* agg  = (float*)(ws + H_BYTES);
    float* t    = (float*)(ws + 2*H_BYTES);
    char*  p    = ws + 2*H_BYTES + T_BYTES;
    float* stat = (float*)p;            p += 4096;      // sums/sumsq/mu/rs
    int*   cnt  = (int*)p;              p += (size_t)NN*4;
    int*   row_off = (int*)p;           p += (size_t)(NN+1)*4 + 60; // keep 4B align slack
    int*   cursor  = (int*)p;           p += (size_t)NN*4;
    int*   packed  = (int*)p;           // EE ints
    float* sums = stat;          // 300
    float* sumsq= stat + 300;    // 300
    float* mu   = stat + 600;    // 300
    float* rs   = stat + 900;    // 300

    // ---- CSR build (once per call; edge structure shared by all layers) ----
    hipMemsetAsync(cnt, 0, (size_t)NN*4, stream);
    k_hist<<<EE/256, 256, 0, stream>>>(ei, cnt);
    k_scan<<<1, 1024, 0, stream>>>(cnt, row_off, cursor);
    k_fill<<<EE/256, 256, 0, stream>>>(ei, eattr, cursor, packed);

    k_init_h<<<NN, 256, 0, stream>>>(x, ta, td, tc, th, tar, tch, h);

    for (int l = 0; l < NL; ++l) {
        k_aggregate<<<NN/4, 256, 0, stream>>>(row_off, packed, h,
                                              ee1 + (size_t)l*6*EMB,
                                              ee2 + (size_t)l*3*EMB, agg);
        k_gemm<true ><<<dim3(10,256), 256, 0, stream>>>(agg, W1 + (size_t)l*EMB*H2,
                                                        b1 + (size_t)l*H2, t,
                                                        NN, EMB, H2);
        k_gemm<false><<<dim3(5,256), 256, 0, stream>>>(t, W2 + (size_t)l*H2*EMB,
                                                       b2 + (size_t)l*EMB, h,
                                                       NN, H2, EMB);
        hipMemsetAsync(stat, 0, 2400, stream);
        k_bnstats<<<NN/128, 320, 0, stream>>>(h, sums, sumsq);
        k_bnfin<<<1, 320, 0, stream>>>(sums, sumsq, mu, rs);
        float* dst = (l == NL-1) ? out : h;
        k_bnapply<<<2048, 256, 0, stream>>>(h, mu, rs,
                                            gam + (size_t)l*EMB, bet + (size_t)l*EMB,
                                            dst, (l < NL-1) ? 1 : 0);
    }
}

// Round 4
// 726.424 us; speedup vs baseline: 3.7325x; 2.0472x over previous
//
#include <hip/hip_runtime.h>

#define NN 16384
#define EE 262144
#define EMB 300
#define H2 600
#define NL 5
#define BN_EPS 1e-5f
#define KP1 320     // GEMM1 K padded (300->320)
#define N1  640     // GEMM1 N padded (600->640)
#define KP2 640     // GEMM2 K padded (=N1)
#define N2  320     // GEMM2 N padded (300->320)

typedef unsigned short u16;
typedef float    f32x4 __attribute__((ext_vector_type(4)));
typedef _Float16 f16x8 __attribute__((ext_vector_type(8)));
typedef unsigned int u32x4 __attribute__((ext_vector_type(4)));

__device__ inline u16 f2h(float f) {              // RNE f32 -> f16
    _Float16 h = (_Float16)f;
    return __builtin_bit_cast(u16, h);
}

__device__ inline void gload16(const u16* g, u16* l) {
    __builtin_amdgcn_global_load_lds((const __attribute__((address_space(1))) void*)g,
                                     (__attribute__((address_space(3))) void*)l, 16, 0, 0);
}

__device__ inline f16x8 ld_frag(const u16* p) {
    u32x4 v = *reinterpret_cast<const u32x4*>(p);
    return __builtin_bit_cast(f16x8, v);
}

// ---------------- init h: sum of 6 embedding lookups ----------------
__global__ void k_init_h(const int* __restrict__ x,
                         const float* __restrict__ ta, const float* __restrict__ td,
                         const float* __restrict__ tc, const float* __restrict__ th,
                         const float* __restrict__ tar, const float* __restrict__ tch,
                         float* __restrict__ h) {
    int i = blockIdx.x;
    int i0 = x[i*6+0], i1 = x[i*6+1], i2 = x[i*6+2];
    int i3 = x[i*6+3], i4 = x[i*6+4], i5 = x[i*6+5];
    const float* p0 = ta  + (size_t)i0*EMB;
    const float* p1 = td  + (size_t)i1*EMB;
    const float* p2 = tc  + (size_t)i2*EMB;
    const float* p3 = th  + (size_t)i3*EMB;
    const float* p4 = tar + (size_t)i4*EMB;
    const float* p5 = tch + (size_t)i5*EMB;
    float* ho = h + (size_t)i*EMB;
    for (int j = threadIdx.x; j < EMB; j += blockDim.x)
        ho[j] = p0[j] + p1[j] + p2[j] + p3[j] + p4[j] + p5[j];
}

// ---------------- weight convert+transpose to f16 [n][k] ----------------
__global__ void k_cvt_w1(const float* __restrict__ W1, u16* __restrict__ w1t) {
    int idx = blockIdx.x*256 + threadIdx.x;
    if (idx >= NL*N1*KP1) return;
    int l = idx / (N1*KP1); int rem = idx % (N1*KP1);
    int n = rem / KP1, k = rem % KP1;
    float v = (n < H2 && k < EMB) ? W1[(size_t)l*EMB*H2 + (size_t)k*H2 + n] : 0.f;
    w1t[idx] = f2h(v);
}
__global__ void k_cvt_w2(const float* __restrict__ W2, u16* __restrict__ w2t) {
    int idx = blockIdx.x*256 + threadIdx.x;
    if (idx >= NL*N2*KP2) return;
    int l = idx / (N2*KP2); int rem = idx % (N2*KP2);
    int n = rem / KP2, k = rem % KP2;
    float v = (n < EMB && k < H2) ? W2[(size_t)l*H2*EMB + (size_t)k*EMB + n] : 0.f;
    w2t[idx] = f2h(v);
}

// ---------------- CSR build ----------------
__global__ void k_hist(const int* __restrict__ ei, int* __restrict__ cnt) {
    int e = blockIdx.x * blockDim.x + threadIdx.x;
    if (e < EE) atomicAdd(&cnt[ei[EE + e]], 1);
}

__global__ __launch_bounds__(1024) void k_scan(const int* __restrict__ cnt,
                                               int* __restrict__ row_off,
                                               int* __restrict__ cursor) {
    __shared__ int lds[1024];
    int t = threadIdx.x;
    int base = t * 16;
    int local[16];
    int total = 0;
    #pragma unroll
    for (int i = 0; i < 16; ++i) { local[i] = cnt[base + i]; total += local[i]; }
    lds[t] = total;
    __syncthreads();
    for (int off = 1; off < 1024; off <<= 1) {
        int v = (t >= off) ? lds[t - off] : 0;
        __syncthreads();
        lds[t] += v;
        __syncthreads();
    }
    int run = lds[t] - total;
    #pragma unroll
    for (int i = 0; i < 16; ++i) {
        row_off[base + i] = run;
        cursor[base + i]  = run;
        run += local[i];
    }
    if (t == 0) row_off[NN] = EE;
}

__global__ void k_fill(const int* __restrict__ ei, const int* __restrict__ eattr,
                       int* __restrict__ cursor, int* __restrict__ packed) {
    int e = blockIdx.x * blockDim.x + threadIdx.x;
    if (e >= EE) return;
    int d  = ei[EE + e];
    int s  = ei[e];
    int a0 = eattr[2*e], a1 = eattr[2*e + 1];
    int pos = atomicAdd(&cursor[d], 1);
    packed[pos] = s | ((a0*3 + a1) << 16);
}

// ---------------- per-node gather aggregation -> f16 agg [NN][KP1] ----------------
__global__ __launch_bounds__(256) void k_aggregate(const int* __restrict__ row_off,
                                                   const int* __restrict__ packed,
                                                   const float* __restrict__ h,
                                                   const float* __restrict__ E1,
                                                   const float* __restrict__ E2,
                                                   u16* __restrict__ agg) {
    __shared__ float comb[10 * EMB];
    int tid = threadIdx.x;
    for (int idx = tid; idx < 10 * EMB; idx += 256) {
        int r = idx / EMB, c = idx % EMB;
        float v;
        if (r < 9) v = E1[(r/3)*EMB + c] + E2[(r%3)*EMB + c];
        else       v = E1[4*EMB + c]     + E2[0*EMB + c];
        comb[idx] = v;
    }
    __syncthreads();

    int n    = blockIdx.x * 4 + (tid >> 6);
    int lane = tid & 63;
    float acc[5];
    const float* hn = h + (size_t)n*EMB;
    #pragma unroll
    for (int k = 0; k < 5; ++k) {
        int c = lane + 64*k;
        acc[k] = (c < EMB) ? (hn[c] + comb[9*EMB + c]) : 0.f;
    }
    int j0 = row_off[n], j1 = row_off[n+1];
    for (int j = j0; j < j1; ++j) {
        int p = packed[j];
        int s = p & 0xFFFF;
        int cb = p >> 16;
        const float* hs = h + (size_t)s*EMB;
        const float* cc = comb + cb*EMB;
        #pragma unroll
        for (int k = 0; k < 5; ++k) {
            int c = lane + 64*k;
            if (c < EMB) acc[k] += hs[c] + cc[c];
        }
    }
    u16* ao = agg + (size_t)n*KP1;
    #pragma unroll
    for (int k = 0; k < 5; ++k) {
        int c = lane + 64*k;
        if (c < KP1) ao[c] = (c < EMB) ? f2h(acc[k]) : (u16)0;
    }
}

// ---------------- f16 MFMA GEMM: C = op(A @ Bt^T + bias) ----------------
// A [M][KP] f16 row-major; Bt [Npad][KP] f16 (k-contiguous). 128 x BLKN tile,
// 4 waves (2x2), BK=32, mfma_f32_16x16x32_f16. m97-style 2-barrier loop.
template<int BLKN, bool RELU, bool OUTF16>
__global__ __launch_bounds__(256) void k_mgemm(const u16* __restrict__ A,
                                               const u16* __restrict__ Bt,
                                               const float* __restrict__ bias, int nbias,
                                               void* __restrict__ Cout, int ldc, int ncols,
                                               int KP) {
    constexpr int BW = BLKN / 2;     // wave n-width
    constexpr int NF = BW / 16;      // n-fragments per wave
    __shared__ u16 As[128 * 32];
    __shared__ u16 Bs[BLKN * 32];
    int tid  = threadIdx.x;
    int wv   = tid >> 6, lane = tid & 63;
    int wr   = wv >> 1,  wc   = wv & 1;
    int m0   = blockIdx.y * 128, n0 = blockIdx.x * BLKN;

    f32x4 acc[4][NF];
    f32x4 zz = {0.f, 0.f, 0.f, 0.f};
    #pragma unroll
    for (int i = 0; i < 4; ++i)
        #pragma unroll
        for (int j = 0; j < NF; ++j) acc[i][j] = zz;

    int lrow = tid >> 2, lchk = (tid & 3) * 8;
    for (int k0 = 0; k0 < KP; k0 += 32) {
        // stage A-tile 128x32 (2 issues) and B-tile BLKNx32
        gload16(A + (size_t)(m0 + lrow)      * KP + k0 + lchk, &As[tid * 8]);
        gload16(A + (size_t)(m0 + 64 + lrow) * KP + k0 + lchk, &As[2048 + tid * 8]);
        gload16(Bt + (size_t)(n0 + lrow)     * KP + k0 + lchk, &Bs[tid * 8]);
        if (BLKN == 128)
            gload16(Bt + (size_t)(n0 + 64 + lrow) * KP + k0 + lchk, &Bs[2048 + tid * 8]);
        __syncthreads();

        f16x8 af[4], bfr[NF];
        int rA = lane & 15, kq = (lane >> 4) * 8;
        #pragma unroll
        for (int mf = 0; mf < 4; ++mf)
            af[mf] = ld_frag(&As[(wr*64 + mf*16 + rA) * 32 + kq]);
        #pragma unroll
        for (int nf = 0; nf < NF; ++nf)
            bfr[nf] = ld_frag(&Bs[(wc*BW + nf*16 + rA) * 32 + kq]);
        #pragma unroll
        for (int mf = 0; mf < 4; ++mf)
            #pragma unroll
            for (int nf = 0; nf < NF; ++nf)
                acc[mf][nf] = __builtin_amdgcn_mfma_f32_16x16x32_f16(
                    af[mf], bfr[nf], acc[mf][nf], 0, 0, 0);
        __syncthreads();
    }

    // epilogue: C row = (lane>>4)*4 + reg, col = lane&15  (m89/m91 layout)
    int rq = (lane >> 4) * 4, cn = lane & 15;
    #pragma unroll
    for (int nf = 0; nf < NF; ++nf) {
        int n = n0 + wc*BW + nf*16 + cn;
        float bv = (n < nbias) ? bias[n] : 0.f;
        #pragma unroll
        for (int mf = 0; mf < 4; ++mf) {
            #pragma unroll
            for (int r = 0; r < 4; ++r) {
                int m = m0 + wr*64 + mf*16 + rq + r;
                float v = acc[mf][nf][r] + bv;
                if (RELU) v = fmaxf(v, 0.f);
                if (OUTF16) {
                    ((u16*)Cout)[(size_t)m * ldc + n] = f2h(v);
                } else {
                    if (n < ncols) ((float*)Cout)[(size_t)m * ldc + n] = v;
                }
            }
        }
    }
}

// ---------------- BN ----------------
__global__ void k_bnstats(const float* __restrict__ h,
                          float* __restrict__ sums, float* __restrict__ sumsq) {
    int c = threadIdx.x;
    if (c >= EMB) return;
    int r0 = blockIdx.x * 128;
    float s = 0.f, s2 = 0.f;
    for (int r = r0; r < r0 + 128; ++r) {
        float v = h[(size_t)r*EMB + c];
        s += v; s2 += v*v;
    }
    atomicAdd(&sums[c], s);
    atomicAdd(&sumsq[c], s2);
}

__global__ void k_bnfin(const float* __restrict__ sums, const float* __restrict__ sumsq,
                        float* __restrict__ mu, float* __restrict__ rs) {
    int c = threadIdx.x;
    if (c >= EMB) return;
    float m = sums[c] * (1.f/NN);
    float v = sumsq[c] * (1.f/NN) - m*m;
    mu[c] = m;
    rs[c] = rsqrtf(v + BN_EPS);
}

__global__ void k_bnapply(const float* __restrict__ h, const float* __restrict__ mu,
                          const float* __restrict__ rs, const float* __restrict__ gamma,
                          const float* __restrict__ beta, float* __restrict__ out, int relu) {
    const int total = NN*EMB;
    for (int idx = blockIdx.x*blockDim.x + threadIdx.x; idx < total;
         idx += gridDim.x*blockDim.x) {
        int c = idx % EMB;
        float v = (h[idx] - mu[c]) * rs[c] * gamma[c] + beta[c];
        if (relu) v = fmaxf(v, 0.f);
        out[idx] = v;
    }
}

extern "C" void kernel_launch(void* const* d_in, const int* in_sizes, int n_in,
                              void* d_out, int out_size, void* d_ws, size_t ws_size,
                              hipStream_t stream) {
    const int*   x     = (const int*)d_in[0];
    const int*   ei    = (const int*)d_in[1];
    const int*   eattr = (const int*)d_in[2];
    const float* ta    = (const float*)d_in[3];
    const float* td    = (const float*)d_in[4];
    const float* tc    = (const float*)d_in[5];
    const float* th    = (const float*)d_in[6];
    const float* tar   = (const float*)d_in[7];
    const float* tch   = (const float*)d_in[8];
    const float* W1    = (const float*)d_in[9];
    const float* b1    = (const float*)d_in[10];
    const float* W2    = (const float*)d_in[11];
    const float* b2    = (const float*)d_in[12];
    const float* ee1   = (const float*)d_in[13];
    const float* ee2   = (const float*)d_in[14];
    const float* gam   = (const float*)d_in[15];
    const float* bet   = (const float*)d_in[16];
    float* out = (float*)d_out;

    char* ws = (char*)d_ws;
    float* h    = (float*)ws;                         ws += (size_t)NN*EMB*4;
    u16*   aggF = (u16*)ws;                           ws += (size_t)NN*KP1*2;
    u16*   t    = (u16*)ws;                           ws += (size_t)NN*N1*2;
    u16*   w1t  = (u16*)ws;                           ws += (size_t)NL*N1*KP1*2;
    u16*   w2t  = (u16*)ws;                           ws += (size_t)NL*N2*KP2*2;
    float* stat = (float*)ws;                         ws += 4096;
    int*   cnt  = (int*)ws;                           ws += (size_t)NN*4;
    int*   row_off = (int*)ws;                        ws += (size_t)(NN+1)*4 + 60;
    int*   cursor  = (int*)ws;                        ws += (size_t)NN*4;
    int*   packed  = (int*)ws;
    float* sums = stat, *sumsq = stat+300, *mu = stat+600, *rs = stat+900;

    // ---- once per call: weight f16 transpose, CSR build, init h ----
    k_cvt_w1<<<(NL*N1*KP1 + 255)/256, 256, 0, stream>>>(W1, w1t);
    k_cvt_w2<<<(NL*N2*KP2 + 255)/256, 256, 0, stream>>>(W2, w2t);
    hipMemsetAsync(cnt, 0, (size_t)NN*4, stream);
    k_hist<<<EE/256, 256, 0, stream>>>(ei, cnt);
    k_scan<<<1, 1024, 0, stream>>>(cnt, row_off, cursor);
    k_fill<<<EE/256, 256, 0, stream>>>(ei, eattr, cursor, packed);
    k_init_h<<<NN, 256, 0, stream>>>(x, ta, td, tc, th, tar, tch, h);

    for (int l = 0; l < NL; ++l) {
        k_aggregate<<<NN/4, 256, 0, stream>>>(row_off, packed, h,
                                              ee1 + (size_t)l*6*EMB,
                                              ee2 + (size_t)l*3*EMB, aggF);
        k_mgemm<128, true, true><<<dim3(N1/128, NN/128), 256, 0, stream>>>(
            aggF, w1t + (size_t)l*N1*KP1, b1 + (size_t)l*H2, H2,
            t, N1, N1, KP1);
        k_mgemm<64, false, false><<<dim3(N2/64, NN/128), 256, 0, stream>>>(
            t, w2t + (size_t)l*N2*KP2, b2 + (size_t)l*EMB, EMB,
            h, EMB, EMB, KP2);
        hipMemsetAsync(stat, 0, 2400, stream);
        k_bnstats<<<NN/128, 320, 0, stream>>>(h, sums, sumsq);
        k_bnfin<<<1, 320, 0, stream>>>(sums, sumsq, mu, rs);
        float* dst = (l == NL-1) ? out : h;
        k_bnapply<<<2048, 256, 0, stream>>>(h, mu, rs,
                                            gam + (size_t)l*EMB, bet + (size_t)l*EMB,
                                            dst, (l < NL-1) ? 1 : 0);
    }
}

// Round 6
// 613.102 us; speedup vs baseline: 4.4224x; 1.1848x over previous
//
#include <hip/hip_runtime.h>

#define NN 16384
#define EE 262144
#define EMB 300
#define H2 600
#define NL 5
#define BN_EPS 1e-5f
#define KP1 320     // GEMM1 K padded (300->320); also hF16/agg row stride
#define N1  640     // GEMM1 N padded (600->640)
#define KP2 640     // GEMM2 K padded (=N1)
#define N2  320     // GEMM2 N padded (300->320)

typedef unsigned short u16;
typedef unsigned int   u32;
typedef float    f32x4 __attribute__((ext_vector_type(4)));
typedef _Float16 f16x8 __attribute__((ext_vector_type(8)));
typedef _Float16 f16x2 __attribute__((ext_vector_type(2)));
typedef unsigned int u32x4 __attribute__((ext_vector_type(4)));

__device__ inline u16 f2h(float f) {
    _Float16 h = (_Float16)f;
    return __builtin_bit_cast(u16, h);
}
__device__ inline u32 packh2(float x, float y) {
    f16x2 p; p.x = (_Float16)x; p.y = (_Float16)y;
    return __builtin_bit_cast(u32, p);
}

__device__ inline void gload16(const u16* g, u16* l) {
    __builtin_amdgcn_global_load_lds((const __attribute__((address_space(1))) void*)g,
                                     (__attribute__((address_space(3))) void*)l, 16, 0, 0);
}

__device__ inline f16x8 ld_frag(const u16* p) {
    u32x4 v = *reinterpret_cast<const u32x4*>(p);
    return __builtin_bit_cast(f16x8, v);
}

// ---------------- init h (f16, padded rows) ----------------
__global__ void k_init_h(const int* __restrict__ x,
                         const float* __restrict__ ta, const float* __restrict__ td,
                         const float* __restrict__ tc, const float* __restrict__ th,
                         const float* __restrict__ tar, const float* __restrict__ tch,
                         u16* __restrict__ hF) {
    int i = blockIdx.x;
    int j = threadIdx.x;                 // 320 threads
    u16 o = 0;
    if (j < EMB) {
        float v = ta [(size_t)x[i*6+0]*EMB + j] + td [(size_t)x[i*6+1]*EMB + j]
                + tc [(size_t)x[i*6+2]*EMB + j] + th [(size_t)x[i*6+3]*EMB + j]
                + tar[(size_t)x[i*6+4]*EMB + j] + tch[(size_t)x[i*6+5]*EMB + j];
        o = f2h(v);
    }
    hF[(size_t)i*KP1 + j] = o;
}

// ---------------- weight convert+transpose to f16 [n][k] ----------------
__global__ void k_cvt_w1(const float* __restrict__ W1, u16* __restrict__ w1t) {
    int idx = blockIdx.x*256 + threadIdx.x;
    if (idx >= NL*N1*KP1) return;
    int l = idx / (N1*KP1); int rem = idx % (N1*KP1);
    int n = rem / KP1, k = rem % KP1;
    float v = (n < H2 && k < EMB) ? W1[(size_t)l*EMB*H2 + (size_t)k*H2 + n] : 0.f;
    w1t[idx] = f2h(v);
}
__global__ void k_cvt_w2(const float* __restrict__ W2, u16* __restrict__ w2t) {
    int idx = blockIdx.x*256 + threadIdx.x;
    if (idx >= NL*N2*KP2) return;
    int l = idx / (N2*KP2); int rem = idx % (N2*KP2);
    int n = rem / KP2, k = rem % KP2;
    float v = (n < EMB && k < H2) ? W2[(size_t)l*H2*EMB + (size_t)k*EMB + n] : 0.f;
    w2t[idx] = f2h(v);
}

// ---------------- CSR build ----------------
__global__ void k_hist(const int* __restrict__ ei, int* __restrict__ cnt) {
    int e = blockIdx.x * blockDim.x + threadIdx.x;
    if (e < EE) atomicAdd(&cnt[ei[EE + e]], 1);
}

__global__ __launch_bounds__(1024) void k_scan(const int* __restrict__ cnt,
                                               int* __restrict__ row_off,
                                               int* __restrict__ cursor) {
    __shared__ int lds[1024];
    int t = threadIdx.x;
    int base = t * 16;
    int local[16];
    int total = 0;
    #pragma unroll
    for (int i = 0; i < 16; ++i) { local[i] = cnt[base + i]; total += local[i]; }
    lds[t] = total;
    __syncthreads();
    for (int off = 1; off < 1024; off <<= 1) {
        int v = (t >= off) ? lds[t - off] : 0;
        __syncthreads();
        lds[t] += v;
        __syncthreads();
    }
    int run = lds[t] - total;
    #pragma unroll
    for (int i = 0; i < 16; ++i) {
        row_off[base + i] = run;
        cursor[base + i]  = run;
        run += local[i];
    }
    if (t == 0) row_off[NN] = EE;
}

__global__ void k_fill(const int* __restrict__ ei, const int* __restrict__ eattr,
                       int* __restrict__ cursor, int* __restrict__ packed) {
    int e = blockIdx.x * blockDim.x + threadIdx.x;
    if (e >= EE) return;
    int d  = ei[EE + e];
    int s  = ei[e];
    int a0 = eattr[2*e], a1 = eattr[2*e + 1];
    int pos = atomicAdd(&cursor[d], 1);
    packed[pos] = s | ((a0*3 + a1) << 16);
}

// ---------------- per-node gather aggregation: f16 h -> f16 agg ----------------
// 1024 blocks x 4 waves; each wave handles 4 nodes (grid-stride by 4096).
// Channels viewed as u32 (f16 pairs): 150 active u32 per row, rows padded to 160.
__global__ __launch_bounds__(256) void k_aggregate(const int* __restrict__ row_off,
                                                   const int* __restrict__ packed,
                                                   const u16* __restrict__ hF,
                                                   const float* __restrict__ E1,
                                                   const float* __restrict__ E2,
                                                   u16* __restrict__ agg) {
    __shared__ float comb[10 * EMB];
    int tid = threadIdx.x;
    for (int idx = tid; idx < 10 * EMB; idx += 256) {
        int r = idx / EMB, c = idx % EMB;
        comb[idx] = (r < 9) ? (E1[(r/3)*EMB + c] + E2[(r%3)*EMB + c])
                            : (E1[4*EMB + c]     + E2[0*EMB + c]);
    }
    __syncthreads();

    int wv = tid >> 6, lane = tid & 63;
    int c0 = lane, c1 = lane + 64, c2 = lane + 128;   // u32 chunk indices
    bool a2 = (c2 < 150);          // c0,c1 always active data
    bool w2r = (c2 < 160);         // c2 within row (chunks 150..159 = zero pad)

    for (int it = 0; it < 4; ++it) {
        int n = blockIdx.x * 4 + wv + it * 4096;
        float x0, y0, x1, y1, x2 = 0.f, y2 = 0.f;
        {   // self-loop init: h[n] + comb[9]
            const u32* hn = (const u32*)(hF + (size_t)n*KP1);
            f16x2 v0 = __builtin_bit_cast(f16x2, hn[c0]);
            f16x2 v1 = __builtin_bit_cast(f16x2, hn[c1]);
            x0 = (float)v0.x + comb[9*EMB + 2*c0];
            y0 = (float)v0.y + comb[9*EMB + 2*c0 + 1];
            x1 = (float)v1.x + comb[9*EMB + 2*c1];
            y1 = (float)v1.y + comb[9*EMB + 2*c1 + 1];
            if (a2) {
                f16x2 v2 = __builtin_bit_cast(f16x2, hn[c2]);
                x2 = (float)v2.x + comb[9*EMB + 2*c2];
                y2 = (float)v2.y + comb[9*EMB + 2*c2 + 1];
            }
        }
        int j0 = row_off[n], j1 = row_off[n+1];
        int j = j0;
        for (; j + 1 < j1; j += 2) {       // 2x unroll for outstanding loads
            int pA = packed[j], pB = packed[j+1];
            const u32* hA = (const u32*)(hF + (size_t)(pA & 0xFFFF)*KP1);
            const u32* hB = (const u32*)(hF + (size_t)(pB & 0xFFFF)*KP1);
            const float* cA = comb + (pA >> 16)*EMB;
            const float* cB = comb + (pB >> 16)*EMB;
            u32 rA0 = hA[c0], rA1 = hA[c1], rB0 = hB[c0], rB1 = hB[c1];
            u32 rA2 = 0, rB2 = 0;
            if (a2) { rA2 = hA[c2]; rB2 = hB[c2]; }
            f16x2 v;
            v = __builtin_bit_cast(f16x2, rA0); x0 += (float)v.x + cA[2*c0]; y0 += (float)v.y + cA[2*c0+1];
            v = __builtin_bit_cast(f16x2, rA1); x1 += (float)v.x + cA[2*c1]; y1 += (float)v.y + cA[2*c1+1];
            v = __builtin_bit_cast(f16x2, rB0); x0 += (float)v.x + cB[2*c0]; y0 += (float)v.y + cB[2*c0+1];
            v = __builtin_bit_cast(f16x2, rB1); x1 += (float)v.x + cB[2*c1]; y1 += (float)v.y + cB[2*c1+1];
            if (a2) {
                v = __builtin_bit_cast(f16x2, rA2); x2 += (float)v.x + cA[2*c2]; y2 += (float)v.y + cA[2*c2+1];
                v = __builtin_bit_cast(f16x2, rB2); x2 += (float)v.x + cB[2*c2]; y2 += (float)v.y + cB[2*c2+1];
            }
        }
        if (j < j1) {
            int pA = packed[j];
            const u32* hA = (const u32*)(hF + (size_t)(pA & 0xFFFF)*KP1);
            const float* cA = comb + (pA >> 16)*EMB;
            f16x2 v;
            v = __builtin_bit_cast(f16x2, hA[c0]); x0 += (float)v.x + cA[2*c0]; y0 += (float)v.y + cA[2*c0+1];
            v = __builtin_bit_cast(f16x2, hA[c1]); x1 += (float)v.x + cA[2*c1]; y1 += (float)v.y + cA[2*c1+1];
            if (a2) {
                v = __builtin_bit_cast(f16x2, hA[c2]); x2 += (float)v.x + cA[2*c2]; y2 += (float)v.y + cA[2*c2+1];
            }
        }
        u32* ao = (u32*)(agg + (size_t)n*KP1);
        ao[c0] = packh2(x0, y0);
        ao[c1] = packh2(x1, y1);
        if (w2r) ao[c2] = a2 ? packh2(x2, y2) : 0u;   // chunks [128,160) only; NO write past row
    }
}

// ---------------- f16 MFMA GEMM: C = op(A @ Bt^T + bias) ----------------
template<int BLKN, bool RELU, bool OUTF16>
__global__ __launch_bounds__(256) void k_mgemm(const u16* __restrict__ A,
                                               const u16* __restrict__ Bt,
                                               const float* __restrict__ bias, int nbias,
                                               void* __restrict__ Cout, int ldc, int ncols,
                                               int KP) {
    constexpr int BW = BLKN / 2;
    constexpr int NF = BW / 16;
    __shared__ u16 As[128 * 32];
    __shared__ u16 Bs[BLKN * 32];
    int tid  = threadIdx.x;
    int wv   = tid >> 6, lane = tid & 63;
    int wr   = wv >> 1,  wc   = wv & 1;
    int m0   = blockIdx.y * 128, n0 = blockIdx.x * BLKN;

    f32x4 acc[4][NF];
    f32x4 zz = {0.f, 0.f, 0.f, 0.f};
    #pragma unroll
    for (int i = 0; i < 4; ++i)
        #pragma unroll
        for (int j = 0; j < NF; ++j) acc[i][j] = zz;

    int lrow = tid >> 2, lchk = (tid & 3) * 8;
    for (int k0 = 0; k0 < KP; k0 += 32) {
        gload16(A + (size_t)(m0 + lrow)      * KP + k0 + lchk, &As[tid * 8]);
        gload16(A + (size_t)(m0 + 64 + lrow) * KP + k0 + lchk, &As[2048 + tid * 8]);
        gload16(Bt + (size_t)(n0 + lrow)     * KP + k0 + lchk, &Bs[tid * 8]);
        if (BLKN == 128)
            gload16(Bt + (size_t)(n0 + 64 + lrow) * KP + k0 + lchk, &Bs[2048 + tid * 8]);
        __syncthreads();

        f16x8 af[4], bfr[NF];
        int rA = lane & 15, kq = (lane >> 4) * 8;
        #pragma unroll
        for (int mf = 0; mf < 4; ++mf)
            af[mf] = ld_frag(&As[(wr*64 + mf*16 + rA) * 32 + kq]);
        #pragma unroll
        for (int nf = 0; nf < NF; ++nf)
            bfr[nf] = ld_frag(&Bs[(wc*BW + nf*16 + rA) * 32 + kq]);
        #pragma unroll
        for (int mf = 0; mf < 4; ++mf)
            #pragma unroll
            for (int nf = 0; nf < NF; ++nf)
                acc[mf][nf] = __builtin_amdgcn_mfma_f32_16x16x32_f16(
                    af[mf], bfr[nf], acc[mf][nf], 0, 0, 0);
        __syncthreads();
    }

    int rq = (lane >> 4) * 4, cn = lane & 15;
    #pragma unroll
    for (int nf = 0; nf < NF; ++nf) {
        int n = n0 + wc*BW + nf*16 + cn;
        float bv = (n < nbias) ? bias[n] : 0.f;
        #pragma unroll
        for (int mf = 0; mf < 4; ++mf) {
            #pragma unroll
            for (int r = 0; r < 4; ++r) {
                int m = m0 + wr*64 + mf*16 + rq + r;
                float v = acc[mf][nf][r] + bv;
                if (RELU) v = fmaxf(v, 0.f);
                if (OUTF16) {
                    ((u16*)Cout)[(size_t)m * ldc + n] = f2h(v);
                } else {
                    if (n < ncols) ((float*)Cout)[(size_t)m * ldc + n] = v;
                }
            }
        }
    }
}

// ---------------- BN ----------------
__global__ void k_bnstats(const float* __restrict__ h,
                          float* __restrict__ sums, float* __restrict__ sumsq) {
    int c = threadIdx.x;
    if (c >= EMB) return;
    int r0 = blockIdx.x * 128;
    float s = 0.f, s2 = 0.f;
    for (int r = r0; r < r0 + 128; ++r) {
        float v = h[(size_t)r*EMB + c];
        s += v; s2 += v*v;
    }
    atomicAdd(&sums[c], s);
    atomicAdd(&sumsq[c], s2);
}

__global__ void k_bnfin(const float* __restrict__ sums, const float* __restrict__ sumsq,
                        float* __restrict__ mu, float* __restrict__ rs) {
    int c = threadIdx.x;
    if (c >= EMB) return;
    float m = sums[c] * (1.f/NN);
    float v = sumsq[c] * (1.f/NN) - m*m;
    mu[c] = m;
    rs[c] = rsqrtf(v + BN_EPS);
}

// layers 0..3: normalize + affine + ReLU -> f16 padded hF
__global__ void k_bnapply_f16(const float* __restrict__ h, const float* __restrict__ mu,
                              const float* __restrict__ rs, const float* __restrict__ gamma,
                              const float* __restrict__ beta, u16* __restrict__ hF) {
    const int total = NN*KP1;
    for (int idx = blockIdx.x*blockDim.x + threadIdx.x; idx < total;
         idx += gridDim.x*blockDim.x) {
        int c = idx % KP1, r = idx / KP1;
        u16 o = 0;
        if (c < EMB) {
            float v = (h[(size_t)r*EMB + c] - mu[c]) * rs[c] * gamma[c] + beta[c];
            o = f2h(fmaxf(v, 0.f));
        }
        hF[idx] = o;
    }
}

// last layer: normalize + affine (no ReLU) -> f32 out
__global__ void k_bnapply_f32(const float* __restrict__ h, const float* __restrict__ mu,
                              const float* __restrict__ rs, const float* __restrict__ gamma,
                              const float* __restrict__ beta, float* __restrict__ out) {
    const int total = NN*EMB;
    for (int idx = blockIdx.x*blockDim.x + threadIdx.x; idx < total;
         idx += gridDim.x*blockDim.x) {
        int c = idx % EMB;
        out[idx] = (h[idx] - mu[c]) * rs[c] * gamma[c] + beta[c];
    }
}

extern "C" void kernel_launch(void* const* d_in, const int* in_sizes, int n_in,
                              void* d_out, int out_size, void* d_ws, size_t ws_size,
                              hipStream_t stream) {
    const int*   x     = (const int*)d_in[0];
    const int*   ei    = (const int*)d_in[1];
    const int*   eattr = (const int*)d_in[2];
    const float* ta    = (const float*)d_in[3];
    const float* td    = (const float*)d_in[4];
    const float* tc    = (const float*)d_in[5];
    const float* th    = (const float*)d_in[6];
    const float* tar   = (const float*)d_in[7];
    const float* tch   = (const float*)d_in[8];
    const float* W1    = (const float*)d_in[9];
    const float* b1    = (const float*)d_in[10];
    const float* W2    = (const float*)d_in[11];
    const float* b2    = (const float*)d_in[12];
    const float* ee1   = (const float*)d_in[13];
    const float* ee2   = (const float*)d_in[14];
    const float* gam   = (const float*)d_in[15];
    const float* bet   = (const float*)d_in[16];
    float* out = (float*)d_out;

    char* ws = (char*)d_ws;
    float* hP   = (float*)ws;                         ws += (size_t)NN*EMB*4;   // pre-BN h (f32)
    u16*   hF   = (u16*)ws;                           ws += (size_t)NN*KP1*2;   // post-BN h (f16)
    u16*   aggF = (u16*)ws;                           ws += (size_t)NN*KP1*2;
    u16*   t    = (u16*)ws;                           ws += (size_t)NN*N1*2;
    u16*   w1t  = (u16*)ws;                           ws += (size_t)NL*N1*KP1*2;
    u16*   w2t  = (u16*)ws;                           ws += (size_t)NL*N2*KP2*2;
    float* stat = (float*)ws;                         ws += 4096;
    int*   cnt  = (int*)ws;                           ws += (size_t)NN*4;
    int*   row_off = (int*)ws;                        ws += (size_t)(NN+1)*4 + 60;
    int*   cursor  = (int*)ws;                        ws += (size_t)NN*4;
    int*   packed  = (int*)ws;
    float* sums = stat, *sumsq = stat+300, *mu = stat+600, *rs = stat+900;

    // ---- once per call: weight f16 transpose, CSR build, init h ----
    k_cvt_w1<<<(NL*N1*KP1 + 255)/256, 256, 0, stream>>>(W1, w1t);
    k_cvt_w2<<<(NL*N2*KP2 + 255)/256, 256, 0, stream>>>(W2, w2t);
    hipMemsetAsync(cnt, 0, (size_t)NN*4, stream);
    k_hist<<<EE/256, 256, 0, stream>>>(ei, cnt);
    k_scan<<<1, 1024, 0, stream>>>(cnt, row_off, cursor);
    k_fill<<<EE/256, 256, 0, stream>>>(ei, eattr, cursor, packed);
    k_init_h<<<NN, KP1, 0, stream>>>(x, ta, td, tc, th, tar, tch, hF);

    for (int l = 0; l < NL; ++l) {
        k_aggregate<<<1024, 256, 0, stream>>>(row_off, packed, hF,
                                              ee1 + (size_t)l*6*EMB,
                                              ee2 + (size_t)l*3*EMB, aggF);
        k_mgemm<128, true, true><<<dim3(N1/128, NN/128), 256, 0, stream>>>(
            aggF, w1t + (size_t)l*N1*KP1, b1 + (size_t)l*H2, H2,
            t, N1, N1, KP1);
        k_mgemm<64, false, false><<<dim3(N2/64, NN/128), 256, 0, stream>>>(
            t, w2t + (size_t)l*N2*KP2, b2 + (size_t)l*EMB, EMB,
            hP, EMB, EMB, KP2);
        hipMemsetAsync(stat, 0, 2400, stream);
        k_bnstats<<<NN/128, 320, 0, stream>>>(hP, sums, sumsq);
        k_bnfin<<<1, 320, 0, stream>>>(sums, sumsq, mu, rs);
        if (l < NL-1)
            k_bnapply_f16<<<2048, 256, 0, stream>>>(hP, mu, rs,
                                                    gam + (size_t)l*EMB, bet + (size_t)l*EMB, hF);
        else
            k_bnapply_f32<<<2048, 256, 0, stream>>>(hP, mu, rs,
                                                    gam + (size_t)l*EMB, bet + (size_t)l*EMB, out);
    }
}